// Round 3
// baseline (669.091 us; speedup 1.0000x reference)
//
#include <hip/hip_runtime.h>

#define N_NODES 100000
#define N_EDGES 3200000
#define IN_DIM 20
#define HIDDEN 4096
#define OUT_DIM 2
#define BN_EPS 1e-5f

// ---------------- workspace layout (byte offsets into d_ws) ----------------
// deg   : int  [100000]   @ 0         (400000 B)
// dinv  : float[100000]   @ 400000    (400000 B)
// agg   : float[2000000]  @ 800000    (8000000 B)
// S1    : float[20]       @ 8800000
// S2    : float[400]      @ 8800080
// mean  : float[20]       @ 8801680
// cov   : float[400]      @ 8801760
// agg0c : float[20]       @ 8803360
// W2    : float[40]       @ 8803440   (W2[2t+k])
// dvec  : float[2]        @ 8803600
// total ~8.81 MB

__global__ void k_deg(const int* __restrict__ ei, int* __restrict__ deg) {
    int e = blockIdx.x * blockDim.x + threadIdx.x;
    if (e < N_EDGES) {
        int c = ei[N_EDGES + e];   // col
        atomicAdd(&deg[c], 1);
    }
}

__global__ void k_dinv(const int* __restrict__ deg, float* __restrict__ dinv) {
    int i = blockIdx.x * blockDim.x + threadIdx.x;
    if (i < N_NODES) dinv[i] = rsqrtf((float)(deg[i] + 1));  // +1 self loop; always > 0
}

// self-loop contribution: agg[i] = nf[i] * dinv[i]^2  (also serves as the zero-init)
__global__ void k_agginit(const float* __restrict__ nf, const float* __restrict__ dinv,
                          float* __restrict__ agg) {
    int t = blockIdx.x * blockDim.x + threadIdx.x;
    if (t < N_NODES * IN_DIM) {
        int i = t / IN_DIM;
        float d = dinv[i];
        agg[t] = nf[t] * d * d;
    }
}

// one thread per (edge, feature): agg[col] += nf[row] * dinv[row]*dinv[col]
__global__ void k_scatter(const int* __restrict__ ei, const float* __restrict__ nf,
                          const float* __restrict__ dinv, float* __restrict__ agg) {
    int t = blockIdx.x * blockDim.x + threadIdx.x;
    if (t >= N_EDGES * IN_DIM) return;
    int e = t / IN_DIM;
    int f = t - e * IN_DIM;
    int r = ei[e];
    int c = ei[N_EDGES + e];
    float w = dinv[r] * dinv[c];
    atomicAdd(&agg[c * IN_DIM + f], nf[r * IN_DIM + f] * w);
}

// second-moment reduction: blockIdx.y = a in [0,20]; a<20 -> S2[a][:], a==20 -> S1[:]
__global__ void k_moments(const float* __restrict__ agg, float* __restrict__ S1,
                          float* __restrict__ S2) {
    int a = blockIdx.y;
    float acc[IN_DIM];
#pragma unroll
    for (int b = 0; b < IN_DIM; b++) acc[b] = 0.f;
    int stride = gridDim.x * blockDim.x;
    for (int i = blockIdx.x * blockDim.x + threadIdx.x; i < N_NODES; i += stride) {
        float v[IN_DIM];
#pragma unroll
        for (int b = 0; b < IN_DIM; b++) v[b] = agg[i * IN_DIM + b];
        // avoid runtime-indexed register array (scratch!): re-load v[a] from cache
        float va = (a < IN_DIM) ? agg[i * IN_DIM + a] : 1.0f;
#pragma unroll
        for (int b = 0; b < IN_DIM; b++) acc[b] += va * v[b];
    }
#pragma unroll
    for (int b = 0; b < IN_DIM; b++) {
        float v = acc[b];
#pragma unroll
        for (int s = 32; s > 0; s >>= 1) v += __shfl_down(v, s);
        acc[b] = v;
    }
    if ((threadIdx.x & 63) == 0) {
        float* dst = (a < IN_DIM) ? (S2 + a * IN_DIM) : S1;
#pragma unroll
        for (int b = 0; b < IN_DIM; b++) atomicAdd(&dst[b], acc[b]);
    }
}

__global__ void k_stats(const float* __restrict__ S1, const float* __restrict__ S2,
                        const float* __restrict__ agg, float* __restrict__ mean,
                        float* __restrict__ cov, float* __restrict__ agg0c) {
    int t = threadIdx.x;  // 64 threads
    const float invn = 1.0f / (float)N_NODES;
    if (t < IN_DIM) {
        float m = S1[t] * invn;
        mean[t] = m;
        agg0c[t] = agg[t] - m;  // agg row 0, centered
    }
    __syncthreads();
    for (int idx = t; idx < IN_DIM * IN_DIM; idx += 64) {
        int a = idx / IN_DIM, b = idx - a * IN_DIM;
        cov[idx] = S2[idx] * invn - mean[a] * mean[b];
    }
}

// per hidden unit j: var_j = w_j^T Cov w_j ; a_j = gamma_j*rsqrt(var_j+eps)
// rsu_out[j] = (agg0c @ w_j)*a_j + beta_j
// W2[t][k] += w[t][j]*a_j*lin_w[j][k] ; dvec[k] += beta_j*lin_w[j][k]
__global__ void k_prep(const float* __restrict__ gcn_w, const float* __restrict__ gamma,
                       const float* __restrict__ beta, const float* __restrict__ lin_w,
                       const float* __restrict__ cov, const float* __restrict__ agg0c,
                       float* __restrict__ W2, float* __restrict__ dvec,
                       float* __restrict__ out_rsu) {
    __shared__ float scov[IN_DIM * IN_DIM];
    __shared__ float sa0[IN_DIM];
    int tid = threadIdx.x;
    for (int idx = tid; idx < IN_DIM * IN_DIM; idx += blockDim.x) scov[idx] = cov[idx];
    if (tid < IN_DIM) sa0[tid] = agg0c[tid];
    __syncthreads();
    int j = blockIdx.x * blockDim.x + tid;  // < 4096

    float wcol[IN_DIM];
#pragma unroll
    for (int t = 0; t < IN_DIM; t++) wcol[t] = gcn_w[t * HIDDEN + j];

    float var = 0.f;
#pragma unroll
    for (int t = 0; t < IN_DIM; t++) {
        float s = 0.f;
#pragma unroll
        for (int u = 0; u < IN_DIM; u++) s += scov[t * IN_DIM + u] * wcol[u];
        var += wcol[t] * s;
    }
    float aj = gamma[j] * rsqrtf(var + BN_EPS);

    float e0 = 0.f;
#pragma unroll
    for (int t = 0; t < IN_DIM; t++) e0 += sa0[t] * wcol[t];
    out_rsu[j] = e0 * aj + beta[j];

    float lw0 = lin_w[2 * j], lw1 = lin_w[2 * j + 1];
    float bj = beta[j];
    float vals[42];
#pragma unroll
    for (int t = 0; t < IN_DIM; t++) {
        vals[2 * t]     = wcol[t] * aj * lw0;
        vals[2 * t + 1] = wcol[t] * aj * lw1;
    }
    vals[40] = bj * lw0;
    vals[41] = bj * lw1;
#pragma unroll
    for (int q = 0; q < 42; q++) {
        float v = vals[q];
#pragma unroll
        for (int s = 32; s > 0; s >>= 1) v += __shfl_down(v, s);
        if ((tid & 63) == 0) {
            if (q < 40) atomicAdd(&W2[q], v);
            else        atomicAdd(&dvec[q - 40], v);
        }
    }
}

__global__ void k_final(const float* __restrict__ agg, const float* __restrict__ mean,
                        const float* __restrict__ W2, const float* __restrict__ dvec,
                        const float* __restrict__ lin_b, float* __restrict__ out) {
    int i = blockIdx.x * blockDim.x + threadIdx.x;
    if (i >= N_NODES) return;
    float d0 = dvec[0] + lin_b[0];
    float d1 = dvec[1] + lin_b[1];
#pragma unroll
    for (int t = 0; t < IN_DIM; t++) {
        float v = agg[i * IN_DIM + t] - mean[t];
        d0 += v * W2[2 * t];
        d1 += v * W2[2 * t + 1];
    }
    float l0 = fmaxf(d0, 0.f), l1 = fmaxf(d1, 0.f);
    float m = fmaxf(l0, l1);
    float e0 = expf(l0 - m), e1 = expf(l1 - m);
    float inv = 1.f / (e0 + e1);
    out[2 * i]     = e0 * inv;
    out[2 * i + 1] = e1 * inv;
}

extern "C" void kernel_launch(void* const* d_in, const int* in_sizes, int n_in,
                              void* d_out, int out_size, void* d_ws, size_t ws_size,
                              hipStream_t stream) {
    const float* nf    = (const float*)d_in[0];
    const int*   ei    = (const int*)d_in[1];   // harness stages integer inputs as int32
    const float* gcn_w = (const float*)d_in[2];
    // d_in[3] = gcn_b — cancels inside BN, unused
    const float* gamma = (const float*)d_in[4];
    const float* beta  = (const float*)d_in[5];
    const float* lin_w = (const float*)d_in[6];
    const float* lin_b = (const float*)d_in[7];
    float* out = (float*)d_out;

    char* ws = (char*)d_ws;
    int*   deg  = (int*)(ws + 0);
    float* dinv = (float*)(ws + 400000);
    float* agg  = (float*)(ws + 800000);
    float* S1   = (float*)(ws + 8800000);
    float* S2   = (float*)(ws + 8800080);
    float* mean = (float*)(ws + 8801680);
    float* cov  = (float*)(ws + 8801760);
    float* a0c  = (float*)(ws + 8803360);
    float* W2   = (float*)(ws + 8803440);
    float* dvec = (float*)(ws + 8803600);

    hipMemsetAsync(deg, 0, 400000, stream);
    hipMemsetAsync(S1, 0, 3608, stream);  // S1..dvec contiguous stats block

    k_deg<<<(N_EDGES + 255) / 256, 256, 0, stream>>>(ei, deg);
    k_dinv<<<(N_NODES + 255) / 256, 256, 0, stream>>>(deg, dinv);
    k_agginit<<<(N_NODES * IN_DIM + 255) / 256, 256, 0, stream>>>(nf, dinv, agg);
    k_scatter<<<(N_EDGES * IN_DIM + 255) / 256, 256, 0, stream>>>(ei, nf, dinv, agg);
    dim3 gm(32, IN_DIM + 1);
    k_moments<<<gm, 256, 0, stream>>>(agg, S1, S2);
    k_stats<<<1, 64, 0, stream>>>(S1, S2, agg, mean, cov, a0c);
    k_prep<<<HIDDEN / 256, 256, 0, stream>>>(gcn_w, gamma, beta, lin_w, cov, a0c, W2, dvec,
                                             out + 2 * N_NODES);
    k_final<<<(N_NODES + 255) / 256, 256, 0, stream>>>(agg, mean, W2, dvec, lin_b, out);
}

// Round 5
// 663.894 us; speedup vs baseline: 1.0078x; 1.0078x over previous
//
#include <hip/hip_runtime.h>

#define N_NODES 100000
#define N_EDGES 3200000
#define IN_DIM 20
#define HIDDEN 4096
#define OUT_DIM 2
#define BN_EPS 1e-5f
#define SCAN_CHUNK 1024
#define SCAN_NB 98  // ceil(100000/1024)

// ================= CSR path workspace (byte offsets into d_ws) =================
// deg/cursor : int [100000]    @ 0           (400000)   deg first, reused as cursor
// dinv       : float[100000]   @ 400000      (400000)
// agg        : float[2000000]  @ 800000      (8000000)
// rs         : int [100001]    @ 8800000     (400016 padded)
// csr_row    : int [3200000]   @ 9200016     (12800000)
// blocksum   : int [98]        @ 22000016    (400)
// blockpre   : int [98]        @ 22000416    (400)
// stats      : S1[20] S2[400] mean[20] cov[400] a0c[20] W2[40] dvec[2]
//              @ 22000816 .. 22004424  (3608 B contiguous, memset once)
#define WS_NEED 22004432ull

__global__ void k_deg(const int* __restrict__ ei, int* __restrict__ deg) {
    int e = blockIdx.x * blockDim.x + threadIdx.x;
    if (e < N_EDGES) atomicAdd(&deg[ei[N_EDGES + e]], 1);
}

__global__ void k_dinv(const int* __restrict__ deg, float* __restrict__ dinv) {
    int i = blockIdx.x * blockDim.x + threadIdx.x;
    if (i < N_NODES) dinv[i] = rsqrtf((float)(deg[i] + 1));  // +1 self loop
}

// ---- 3-kernel exclusive scan of deg[100000] -> rs ----
__global__ void k_scan_local(const int* __restrict__ deg, int* __restrict__ rs,
                             int* __restrict__ blocksum) {
    __shared__ int lds[256];
    int b = blockIdx.x, t = threadIdx.x;
    int base = b * SCAN_CHUNK + t * 4;
    int v0 = (base + 0 < N_NODES) ? deg[base + 0] : 0;
    int v1 = (base + 1 < N_NODES) ? deg[base + 1] : 0;
    int v2 = (base + 2 < N_NODES) ? deg[base + 2] : 0;
    int v3 = (base + 3 < N_NODES) ? deg[base + 3] : 0;
    int tsum = v0 + v1 + v2 + v3;
    int x = tsum;
    lds[t] = x;
    __syncthreads();
    for (int off = 1; off < 256; off <<= 1) {
        int y = (t >= off) ? lds[t - off] : 0;
        __syncthreads();
        x += y;
        lds[t] = x;
        __syncthreads();
    }
    int ex = x - tsum;  // exclusive thread prefix
    if (base + 0 < N_NODES) rs[base + 0] = ex;
    if (base + 1 < N_NODES) rs[base + 1] = ex + v0;
    if (base + 2 < N_NODES) rs[base + 2] = ex + v0 + v1;
    if (base + 3 < N_NODES) rs[base + 3] = ex + v0 + v1 + v2;
    if (t == 255) blocksum[b] = x;
}

__global__ void k_scan_mid(const int* __restrict__ blocksum, int* __restrict__ blockpre) {
    __shared__ int lds[128];
    int t = threadIdx.x;
    int v = (t < SCAN_NB) ? blocksum[t] : 0;
    int x = v;
    lds[t] = x;
    __syncthreads();
    for (int off = 1; off < 128; off <<= 1) {
        int y = (t >= off) ? lds[t - off] : 0;
        __syncthreads();
        x += y;
        lds[t] = x;
        __syncthreads();
    }
    if (t < SCAN_NB) blockpre[t] = x - v;
}

__global__ void k_scan_add(int* __restrict__ rs, const int* __restrict__ blockpre,
                           int* __restrict__ cursor) {
    int i = blockIdx.x * blockDim.x + threadIdx.x;
    if (i < N_NODES) {
        int r = rs[i] + blockpre[i >> 10];
        rs[i] = r;
        cursor[i] = r;   // cursor aliases deg; deg no longer needed
    }
    if (i == 0) rs[N_NODES] = N_EDGES;
}

__global__ void k_fill(const int* __restrict__ ei, int* __restrict__ cursor,
                       int* __restrict__ csr_row) {
    int e = blockIdx.x * blockDim.x + threadIdx.x;
    if (e < N_EDGES) {
        int r = ei[e];
        int c = ei[N_EDGES + e];
        int p = atomicAdd(&cursor[c], 1);
        csr_row[p] = r;
    }
}

// gather: 5 threads per node, each owns a float4 feature group; no atomics
__global__ void k_gather(const int* __restrict__ csr_row, const int* __restrict__ rs,
                         const float* __restrict__ nf, const float* __restrict__ dinv,
                         float* __restrict__ agg) {
    int t = blockIdx.x * blockDim.x + threadIdx.x;
    if (t >= N_NODES * 5) return;
    int i = t / 5, g = t % 5;
    const float4* nf4 = (const float4*)nf;
    float di = dinv[i];
    float4 a = nf4[i * 5 + g];
    float s = di * di;  // self-loop term
    a.x *= s; a.y *= s; a.z *= s; a.w *= s;
    int e1 = rs[i + 1];
    for (int e = rs[i]; e < e1; ++e) {
        int r = csr_row[e];
        float w = dinv[r] * di;
        float4 v = nf4[r * 5 + g];
        a.x += v.x * w; a.y += v.y * w; a.z += v.z * w; a.w += v.w * w;
    }
    ((float4*)agg)[i * 5 + g] = a;
}

// moments, 3 rows per block-y: y in [0,7); row index 20 == "ones" (-> S1)
__global__ void k_moments3(const float* __restrict__ agg, float* __restrict__ S1,
                           float* __restrict__ S2) {
    int y = blockIdx.y;
    int a0 = 3 * y, a1 = 3 * y + 1, a2 = 3 * y + 2;  // a0<=18, a1<=19, a2<=20
    float acc0[IN_DIM], acc1[IN_DIM], acc2[IN_DIM];
#pragma unroll
    for (int b = 0; b < IN_DIM; b++) { acc0[b] = 0.f; acc1[b] = 0.f; acc2[b] = 0.f; }
    int stride = gridDim.x * blockDim.x;
    for (int i = blockIdx.x * blockDim.x + threadIdx.x; i < N_NODES; i += stride) {
        const float* row = agg + i * IN_DIM;
        float v[IN_DIM];
#pragma unroll
        for (int b = 0; b < IN_DIM; b++) v[b] = row[b];
        float va0 = row[a0];
        float va1 = row[a1];
        float va2 = (a2 < IN_DIM) ? row[a2] : 1.0f;
#pragma unroll
        for (int b = 0; b < IN_DIM; b++) {
            acc0[b] += va0 * v[b];
            acc1[b] += va1 * v[b];
            acc2[b] += va2 * v[b];
        }
    }
#pragma unroll
    for (int b = 0; b < IN_DIM; b++) {
        float r0 = acc0[b], r1 = acc1[b], r2 = acc2[b];
#pragma unroll
        for (int s = 32; s > 0; s >>= 1) {
            r0 += __shfl_down(r0, s);
            r1 += __shfl_down(r1, s);
            r2 += __shfl_down(r2, s);
        }
        acc0[b] = r0; acc1[b] = r1; acc2[b] = r2;
    }
    if ((threadIdx.x & 63) == 0) {
        float* d0 = S2 + a0 * IN_DIM;
        float* d1 = S2 + a1 * IN_DIM;
        float* d2 = (a2 < IN_DIM) ? (S2 + a2 * IN_DIM) : S1;
#pragma unroll
        for (int b = 0; b < IN_DIM; b++) {
            atomicAdd(&d0[b], acc0[b]);
            atomicAdd(&d1[b], acc1[b]);
            atomicAdd(&d2[b], acc2[b]);
        }
    }
}

__global__ void k_stats(const float* __restrict__ S1, const float* __restrict__ S2,
                        const float* __restrict__ agg, float* __restrict__ mean,
                        float* __restrict__ cov, float* __restrict__ agg0c) {
    int t = threadIdx.x;  // 64 threads
    const float invn = 1.0f / (float)N_NODES;
    if (t < IN_DIM) {
        float m = S1[t] * invn;
        mean[t] = m;
        agg0c[t] = agg[t] - m;
    }
    __syncthreads();
    for (int idx = t; idx < IN_DIM * IN_DIM; idx += 64) {
        int a = idx / IN_DIM, b = idx - a * IN_DIM;
        cov[idx] = S2[idx] * invn - mean[a] * mean[b];
    }
}

__global__ void k_prep(const float* __restrict__ gcn_w, const float* __restrict__ gamma,
                       const float* __restrict__ beta, const float* __restrict__ lin_w,
                       const float* __restrict__ cov, const float* __restrict__ agg0c,
                       float* __restrict__ W2, float* __restrict__ dvec,
                       float* __restrict__ out_rsu) {
    __shared__ float scov[IN_DIM * IN_DIM];
    __shared__ float sa0[IN_DIM];
    int tid = threadIdx.x;
    for (int idx = tid; idx < IN_DIM * IN_DIM; idx += blockDim.x) scov[idx] = cov[idx];
    if (tid < IN_DIM) sa0[tid] = agg0c[tid];
    __syncthreads();
    int j = blockIdx.x * blockDim.x + tid;

    float wcol[IN_DIM];
#pragma unroll
    for (int t = 0; t < IN_DIM; t++) wcol[t] = gcn_w[t * HIDDEN + j];

    float var = 0.f;
#pragma unroll
    for (int t = 0; t < IN_DIM; t++) {
        float s = 0.f;
#pragma unroll
        for (int u = 0; u < IN_DIM; u++) s += scov[t * IN_DIM + u] * wcol[u];
        var += wcol[t] * s;
    }
    float aj = gamma[j] * rsqrtf(var + BN_EPS);

    float e0 = 0.f;
#pragma unroll
    for (int t = 0; t < IN_DIM; t++) e0 += sa0[t] * wcol[t];
    out_rsu[j] = e0 * aj + beta[j];

    float lw0 = lin_w[2 * j], lw1 = lin_w[2 * j + 1];
    float bj = beta[j];
    float vals[42];
#pragma unroll
    for (int t = 0; t < IN_DIM; t++) {
        vals[2 * t]     = wcol[t] * aj * lw0;
        vals[2 * t + 1] = wcol[t] * aj * lw1;
    }
    vals[40] = bj * lw0;
    vals[41] = bj * lw1;
#pragma unroll
    for (int q = 0; q < 42; q++) {
        float v = vals[q];
#pragma unroll
        for (int s = 32; s > 0; s >>= 1) v += __shfl_down(v, s);
        if ((tid & 63) == 0) {
            if (q < 40) atomicAdd(&W2[q], v);
            else        atomicAdd(&dvec[q - 40], v);
        }
    }
}

__global__ void k_final(const float* __restrict__ agg, const float* __restrict__ mean,
                        const float* __restrict__ W2, const float* __restrict__ dvec,
                        const float* __restrict__ lin_b, float* __restrict__ out) {
    int i = blockIdx.x * blockDim.x + threadIdx.x;
    if (i >= N_NODES) return;
    float d0 = dvec[0] + lin_b[0];
    float d1 = dvec[1] + lin_b[1];
#pragma unroll
    for (int t = 0; t < IN_DIM; t++) {
        float v = agg[i * IN_DIM + t] - mean[t];
        d0 += v * W2[2 * t];
        d1 += v * W2[2 * t + 1];
    }
    float l0 = fmaxf(d0, 0.f), l1 = fmaxf(d1, 0.f);
    float m = fmaxf(l0, l1);
    float e0 = expf(l0 - m), e1 = expf(l1 - m);
    float inv = 1.f / (e0 + e1);
    out[2 * i]     = e0 * inv;
    out[2 * i + 1] = e1 * inv;
}

// -------- fallback (scatter) kernels, used only if ws_size < WS_NEED --------
__global__ void k_agginit(const float* __restrict__ nf, const float* __restrict__ dinv,
                          float* __restrict__ agg) {
    int t = blockIdx.x * blockDim.x + threadIdx.x;
    if (t < N_NODES * IN_DIM) {
        int i = t / IN_DIM;
        float d = dinv[i];
        agg[t] = nf[t] * d * d;
    }
}

__global__ void k_scatter(const int* __restrict__ ei, const float* __restrict__ nf,
                          const float* __restrict__ dinv, float* __restrict__ agg) {
    int t = blockIdx.x * blockDim.x + threadIdx.x;
    if (t >= N_EDGES * IN_DIM) return;
    int e = t / IN_DIM;
    int f = t - e * IN_DIM;
    int r = ei[e];
    int c = ei[N_EDGES + e];
    float w = dinv[r] * dinv[c];
    atomicAdd(&agg[c * IN_DIM + f], nf[r * IN_DIM + f] * w);
}

extern "C" void kernel_launch(void* const* d_in, const int* in_sizes, int n_in,
                              void* d_out, int out_size, void* d_ws, size_t ws_size,
                              hipStream_t stream) {
    const float* nf    = (const float*)d_in[0];
    const int*   ei    = (const int*)d_in[1];
    const float* gcn_w = (const float*)d_in[2];
    const float* gamma = (const float*)d_in[4];
    const float* beta  = (const float*)d_in[5];
    const float* lin_w = (const float*)d_in[6];
    const float* lin_b = (const float*)d_in[7];
    float* out = (float*)d_out;

    char* ws = (char*)d_ws;
    int*   deg  = (int*)(ws + 0);        // reused as cursor after scan
    float* dinv = (float*)(ws + 400000);
    float* agg  = (float*)(ws + 800000);

    if (ws_size >= WS_NEED) {
        int* rs       = (int*)(ws + 8800000);
        int* csr_row  = (int*)(ws + 9200016);
        int* blocksum = (int*)(ws + 22000016);
        int* blockpre = (int*)(ws + 22000416);
        float* S1   = (float*)(ws + 22000816);
        float* S2   = (float*)(ws + 22000896);
        float* mean = (float*)(ws + 22002496);
        float* cov  = (float*)(ws + 22002576);
        float* a0c  = (float*)(ws + 22004176);
        float* W2   = (float*)(ws + 22004256);
        float* dvec = (float*)(ws + 22004416);

        hipMemsetAsync(deg, 0, 400000, stream);
        hipMemsetAsync(S1, 0, 3608, stream);

        k_deg<<<(N_EDGES + 255) / 256, 256, 0, stream>>>(ei, deg);
        k_dinv<<<(N_NODES + 255) / 256, 256, 0, stream>>>(deg, dinv);
        k_scan_local<<<SCAN_NB, 256, 0, stream>>>(deg, rs, blocksum);
        k_scan_mid<<<1, 128, 0, stream>>>(blocksum, blockpre);
        k_scan_add<<<(N_NODES + 255) / 256, 256, 0, stream>>>(rs, blockpre, deg);
        k_fill<<<(N_EDGES + 255) / 256, 256, 0, stream>>>(ei, deg, csr_row);
        k_gather<<<(N_NODES * 5 + 255) / 256, 256, 0, stream>>>(csr_row, rs, nf, dinv, agg);
        dim3 gm(32, 7);
        k_moments3<<<gm, 256, 0, stream>>>(agg, S1, S2);
        k_stats<<<1, 64, 0, stream>>>(S1, S2, agg, mean, cov, a0c);
        k_prep<<<HIDDEN / 256, 256, 0, stream>>>(gcn_w, gamma, beta, lin_w, cov, a0c, W2,
                                                 dvec, out + 2 * N_NODES);
        k_final<<<(N_NODES + 255) / 256, 256, 0, stream>>>(agg, mean, W2, dvec, lin_b, out);
    } else {
        float* S1   = (float*)(ws + 8800000);
        float* S2   = (float*)(ws + 8800080);
        float* mean = (float*)(ws + 8801680);
        float* cov  = (float*)(ws + 8801760);
        float* a0c  = (float*)(ws + 8803360);
        float* W2   = (float*)(ws + 8803440);
        float* dvec = (float*)(ws + 8803600);

        hipMemsetAsync(deg, 0, 400000, stream);
        hipMemsetAsync(S1, 0, 3608, stream);

        k_deg<<<(N_EDGES + 255) / 256, 256, 0, stream>>>(ei, deg);
        k_dinv<<<(N_NODES + 255) / 256, 256, 0, stream>>>(deg, dinv);
        k_agginit<<<(N_NODES * IN_DIM + 255) / 256, 256, 0, stream>>>(nf, dinv, agg);
        k_scatter<<<(N_EDGES * IN_DIM + 255) / 256, 256, 0, stream>>>(ei, nf, dinv, agg);
        dim3 gm(32, 7);
        k_moments3<<<gm, 256, 0, stream>>>(agg, S1, S2);
        k_stats<<<1, 64, 0, stream>>>(S1, S2, agg, mean, cov, a0c);
        k_prep<<<HIDDEN / 256, 256, 0, stream>>>(gcn_w, gamma, beta, lin_w, cov, a0c, W2,
                                                 dvec, out + 2 * N_NODES);
        k_final<<<(N_NODES + 255) / 256, 256, 0, stream>>>(agg, mean, W2, dvec, lin_b, out);
    }
}